// Round 7
// baseline (817.564 us; speedup 1.0000x reference)
//
#include <hip/hip_runtime.h>
#include <hip/hip_bf16.h>

#define Hh   128
#define FH   512
#define Lz   64
#define Tt   12
#define NFf  16

typedef __attribute__((ext_vector_type(8))) short short8;   // 8 bf16 = 4 VGPRs
typedef __attribute__((ext_vector_type(4))) float f32x4;

__device__ __forceinline__ float sigf(float x) { return 1.0f / (1.0f + __expf(-x)); }
__device__ __forceinline__ unsigned short f2bf(float x) {
    unsigned u = __float_as_uint(x);
    return (unsigned short)((u + 0x7FFF + ((u >> 16) & 1)) >> 16);
}
__device__ __forceinline__ float bf2f(unsigned short s) {
    return __uint_as_float(((unsigned)s) << 16);
}

// ---------------- graph prep ----------------

__global__ void node_mask_k(const unsigned char* __restrict__ xm, float* __restrict__ mask, int Nn)
{
    int n = blockIdx.x * 256 + threadIdx.x;
    if (n >= Nn) return;
    const unsigned int* p = (const unsigned int*)(xm + (size_t)n * 192);
    unsigned int o = 0;
#pragma unroll
    for (int i = 0; i < 48; ++i) o |= p[i];
    mask[n] = o ? 1.0f : 0.0f;
}

__global__ void deg_count_k(const int* __restrict__ dst, int* __restrict__ degi, int E, int Nn)
{
    int e = blockIdx.x * 256 + threadIdx.x;
    if (e >= E) return;
    int d = dst[e]; d = d < 0 ? 0 : (d >= Nn ? Nn - 1 : d);
    atomicAdd(&degi[d], 1);
}

__global__ void dinv_k(const int* __restrict__ degi, float* __restrict__ dinv, int Nn)
{
    int n = blockIdx.x * 256 + threadIdx.x;
    if (n >= Nn) return;
    dinv[n] = rsqrtf((float)(degi[n] + 1)); // +1 self loop
}

__global__ void scan_k(const int* __restrict__ degi, int* __restrict__ rowptr, int Nn)
{
    __shared__ int wsum[16];
    __shared__ int carry;
    int tid = threadIdx.x;           // 1024
    int lane = tid & 63, wid = tid >> 6;
    if (tid == 0) carry = 0;
    __syncthreads();
    for (int base = 0; base < Nn; base += 1024) {
        int i = base + tid;
        int v = (i < Nn) ? degi[i] : 0;
        int x = v;
#pragma unroll
        for (int off = 1; off < 64; off <<= 1) {
            int y = __shfl_up(x, off, 64);
            if (lane >= off) x += y;
        }
        if (lane == 63) wsum[wid] = x;
        __syncthreads();
        if (wid == 0) {
            int s = (lane < 16) ? wsum[lane] : 0;
#pragma unroll
            for (int off = 1; off < 16; off <<= 1) {
                int y = __shfl_up(s, off, 64);
                if (lane >= off) s += y;
            }
            if (lane < 16) wsum[lane] = s;
        }
        __syncthreads();
        int woff = (wid > 0) ? wsum[wid - 1] : 0;
        int inc = carry + woff + x;
        if (i < Nn) rowptr[i + 1] = inc;
        __syncthreads();
        if (tid == 1023) carry = inc;
        __syncthreads();
    }
    if (tid == 0) rowptr[0] = 0;
}

__global__ void csr_fill_k(const int* __restrict__ src, const int* __restrict__ dst,
                           const float* __restrict__ dinv, const int* __restrict__ rowptr,
                           int* __restrict__ cursor, int* __restrict__ colsrc,
                           float* __restrict__ wnorm, int E, int Nn)
{
    int e = blockIdx.x * 256 + threadIdx.x;
    if (e >= E) return;
    int s = src[e]; s = s < 0 ? 0 : (s >= Nn ? Nn - 1 : s);
    int d = dst[e]; d = d < 0 ? 0 : (d >= Nn ? Nn - 1 : d);
    int pos = rowptr[d] + atomicAdd(&cursor[d], 1);
    colsrc[pos] = s;
    wnorm[pos]  = dinv[s] * dinv[d];
}

// ---------------- weight prep ----------------

// Pack W_hh (bf16 hi only) into MFMA B-fragment order.
// frag (ctile c, ktile kt): lane l elem e holds B[kt*32+(l>>4)*8+e][c*16+(l&15)]
// where B[k][j] = W_hh[j][k].  gid = ((c*4+kt)*64+l)*8+e.
__global__ void pack_whh_k(const float* __restrict__ Whh, unsigned short* __restrict__ Bhi)
{
    int gid = blockIdx.x * 256 + threadIdx.x;     // 65536
    if (gid >= FH * Hh) return;
    int e  = gid & 7;
    int l  = (gid >> 3) & 63;
    int kt = (gid >> 9) & 3;
    int c  = gid >> 11;
    int k = kt * 32 + (l >> 4) * 8 + e;
    int j = c * 16 + (l & 15);
    Bhi[gid] = f2bf(Whh[j * Hh + k]);
}

// Wc = W_gcn @ W_fc3 packed into B-frag order (single ctile, 4 kt), split hi/lo.
// Also bc[f] = b_gcn @ W_fc3 + b_fc3.
__global__ void pack_wc_k(const float* __restrict__ Wg, const float* __restrict__ W3,
                          const float* __restrict__ bg, const float* __restrict__ b3,
                          unsigned short* __restrict__ Wchi, unsigned short* __restrict__ Wclo,
                          float* __restrict__ bc)
{
    int gid = blockIdx.x * 256 + threadIdx.x;
    if (gid < 4096) {
        int e = gid & 7, l = (gid >> 3) & 63, kt = gid >> 9;
        int k = kt * 32 + (l >> 4) * 8 + e, f = l & 15;
        const float* a = Wg + k * Hh;
        float s = 0.f;
#pragma unroll 4
        for (int h = 0; h < Hh; ++h) s += a[h] * W3[h * NFf + f];
        unsigned short hi = f2bf(s);
        Wchi[gid] = hi;
        Wclo[gid] = f2bf(s - bf2f(hi));
    } else if (gid < 4096 + NFf) {
        int f = gid - 4096;
        float s = b3[f];
#pragma unroll 4
        for (int h = 0; h < Hh; ++h) s += bg[h] * W3[h * NFf + f];
        bc[f] = s;
    }
}

// Wz[m][j] = sum_k Wf2[m][k]*Wih[j][k] ; bz[j] = sum_k bf2[k]*Wih[j][k] + bih[j] + bhh[j]
__global__ void fuse_in_k(const float* __restrict__ Wf2, const float* __restrict__ Wih,
                          const float* __restrict__ bf2, const float* __restrict__ bih,
                          const float* __restrict__ bhh,
                          float* __restrict__ Wz, float* __restrict__ bz)
{
    int gid = blockIdx.x * 256 + threadIdx.x;
    if (gid < Lz * FH) {
        int m = gid >> 9, j = gid & 511;
        const float* a = Wf2 + m * Hh;
        const float* b = Wih + j * Hh;
        float s = 0.f;
#pragma unroll 4
        for (int k = 0; k < Hh; ++k) s += a[k] * b[k];
        Wz[m * FH + j] = s;
    } else if (gid < Lz * FH + FH) {
        int j = gid - Lz * FH;
        const float* b = Wih + j * Hh;
        float s = bih[j] + bhh[j];
#pragma unroll 4
        for (int k = 0; k < Hh; ++k) s += bf2[k] * b[k];
        bz[j] = s;
    }
}

// ---------------- fc2: h0 = z @ W_fc2 + b (split bf16 out) ----------------

__global__ __launch_bounds__(128) void fc2_k(const float* __restrict__ z, const float* __restrict__ B,
                                             const float* __restrict__ bias,
                                             unsigned short* __restrict__ h0hi,
                                             unsigned short* __restrict__ h0lo, int Nn)
{
    __shared__ float As[16][Lz];
    int n0 = blockIdx.x * 16;
    int tid = threadIdx.x; // 128
    for (int idx = tid; idx < 16 * Lz; idx += 128) {
        int r = idx >> 6, c = idx & 63;
        int n = n0 + r;
        As[r][c] = (n < Nn) ? z[(size_t)n * Lz + c] : 0.f;
    }
    __syncthreads();
    float acc[16];
#pragma unroll
    for (int i = 0; i < 16; ++i) acc[i] = 0.f;
    for (int k = 0; k < Lz; k += 2) {
        float w0 = B[k * Hh + tid];
        float w1 = B[(k + 1) * Hh + tid];
#pragma unroll
        for (int i = 0; i < 16; ++i) {
            float2 a = *(const float2*)&As[i][k];
            acc[i] += a.x * w0 + a.y * w1;
        }
    }
    float bb = bias[tid];
    for (int i = 0; i < 16; ++i) {
        int n = n0 + i;
        if (n < Nn) {
            float v = acc[i] + bb;
            unsigned short hi = f2bf(v);
            size_t off = (size_t)n * Hh + tid;
            h0hi[off] = hi;
            h0lo[off] = f2bf(v - bf2f(hi));
        }
    }
}

// ---------------- xp2 = z @ Wz + bz (biases folded) ----------------

__global__ __launch_bounds__(128) void xproj_k(const float* __restrict__ A, const float* __restrict__ B,
                                               const float* __restrict__ bias, float* __restrict__ C, int Nn)
{
    __shared__ float As[16][Lz];
    int n0 = blockIdx.x * 16;
    int j = threadIdx.x; // 128
    for (int idx = j; idx < 16 * Lz; idx += 128) {
        int r = idx >> 6, c = idx & 63;
        int n = n0 + r;
        As[r][c] = (n < Nn) ? A[(size_t)n * Lz + c] : 0.f;
    }
    __syncthreads();
    float acc[16][4];
#pragma unroll
    for (int r = 0; r < 16; ++r)
#pragma unroll
        for (int q = 0; q < 4; ++q) acc[r][q] = 0.f;
    for (int k0 = 0; k0 < Lz; k0 += 2) {
        float b0[4], b1[4];
#pragma unroll
        for (int q = 0; q < 4; ++q) {
            b0[q] = B[k0 * FH + q * 128 + j];
            b1[q] = B[(k0 + 1) * FH + q * 128 + j];
        }
#pragma unroll
        for (int r = 0; r < 16; ++r) {
            float2 a = *(const float2*)&As[r][k0];
#pragma unroll
            for (int q = 0; q < 4; ++q) acc[r][q] += a.x * b0[q] + a.y * b1[q];
        }
    }
    float bq[4];
#pragma unroll
    for (int q = 0; q < 4; ++q) bq[q] = bias[q * 128 + j];
    for (int r = 0; r < 16; ++r) {
        int n = n0 + r;
        if (n >= Nn) break;
#pragma unroll
        for (int q = 0; q < 4; ++q) C[(size_t)n * FH + q * 128 + j] = acc[r][q] + bq[q];
    }
}

// ---------------- whole-sequence LSTM + pw, one kernel ----------------
// 256 thr / 4 waves, 32 rows/block, all 12 timesteps internal.
// c in registers (matches C/D layout); h via swizzled 16KB LDS transpose;
// xp2 held in 64 VGPRs (read once); pw = (mask*h) @ Wc by MFMA (Wc frags in regs).

__global__ __launch_bounds__(256, 2) void lstm_all_k(
    const float* __restrict__ xp2,
    const unsigned short* __restrict__ Bhi,
    const unsigned short* __restrict__ Wchi, const unsigned short* __restrict__ Wclo,
    const unsigned short* __restrict__ h0hi, const unsigned short* __restrict__ h0lo,
    const float* __restrict__ mask,
    float* __restrict__ pw, int Nn)
{
    __shared__ float h_s[32][128];   // 16KB, 16B-block XOR swizzle on column
    int tid = threadIdx.x, l = tid & 63, wid = tid >> 6;
    int n0 = blockIdx.x * 32;
    int i0 = l & 15, q = l >> 4;
    int m0 = wid * 2;

    // Wc fragments (held all kernel)
    short8 WcH[4], WcL[4];
#pragma unroll
    for (int kt = 0; kt < 4; ++kt) {
        WcH[kt] = ((const short8*)Wchi)[kt * 64 + l];
        WcL[kt] = ((const short8*)Wclo)[kt * 64 + l];
    }

    // per-rowtile mask (A rows are i0-indexed)
    float mk[2];
#pragma unroll
    for (int rt = 0; rt < 2; ++rt) {
        int n = n0 + rt * 16 + i0;
        mk[rt] = (n < Nn) ? mask[n] : 0.f;
    }

    // xp2 -> registers, once. Cell (rt,mi,r): row n0+rt*16+q*4+r, col (m0+mi)*16+i0, 4 gates.
    float xpr[2][2][4][4];
#pragma unroll
    for (int rt = 0; rt < 2; ++rt)
#pragma unroll
        for (int mi = 0; mi < 2; ++mi) {
            int j = (m0 + mi) * 16 + i0;
#pragma unroll
            for (int r = 0; r < 4; ++r) {
                int n = n0 + rt * 16 + q * 4 + r;
                const float* xp = xp2 + (size_t)n * FH + j;
#pragma unroll
                for (int g = 0; g < 4; ++g)
                    xpr[rt][mi][r][g] = (n < Nn) ? xp[g * 128] : 0.f;
            }
        }

    // initial A-fragments from h0
    short8 Ahi[2][4], Alo[2][4];
#pragma unroll
    for (int rt = 0; rt < 2; ++rt) {
        int row = n0 + rt * 16 + i0; if (row >= Nn) row = Nn - 1;
        const short8* ph = (const short8*)(h0hi + (size_t)row * Hh + q * 8);
        const short8* pl = (const short8*)(h0lo + (size_t)row * Hh + q * 8);
#pragma unroll
        for (int kt = 0; kt < 4; ++kt) { Ahi[rt][kt] = ph[kt * 4]; Alo[rt][kt] = pl[kt * 4]; }
    }

    float cC[2][2][4] = {};   // c state, [rt][mi][r]

    for (int t = 0; t < Tt; ++t) {
        // ---- gates GEMM + pointwise, mi-split to bound registers ----
#pragma unroll
        for (int mi = 0; mi < 2; ++mi) {
            f32x4 acc[2][4];
#pragma unroll
            for (int rt = 0; rt < 2; ++rt)
#pragma unroll
                for (int g = 0; g < 4; ++g) acc[rt][g] = (f32x4){0.f, 0.f, 0.f, 0.f};
#pragma unroll
            for (int g = 0; g < 4; ++g) {
                int cidx = g * 8 + m0 + mi;
#pragma unroll
                for (int kt = 0; kt < 4; ++kt) {
                    short8 b = ((const short8*)Bhi)[((cidx << 2) + kt) * 64 + l];
                    acc[0][g] = __builtin_amdgcn_mfma_f32_16x16x32_bf16(Ahi[0][kt], b, acc[0][g], 0, 0, 0);
                    acc[1][g] = __builtin_amdgcn_mfma_f32_16x16x32_bf16(Ahi[1][kt], b, acc[1][g], 0, 0, 0);
                    acc[0][g] = __builtin_amdgcn_mfma_f32_16x16x32_bf16(Alo[0][kt], b, acc[0][g], 0, 0, 0);
                    acc[1][g] = __builtin_amdgcn_mfma_f32_16x16x32_bf16(Alo[1][kt], b, acc[1][g], 0, 0, 0);
                }
            }
            int j = (m0 + mi) * 16 + i0;
#pragma unroll
            for (int rt = 0; rt < 2; ++rt) {
#pragma unroll
                for (int r = 0; r < 4; ++r) {
                    int i = rt * 16 + q * 4 + r;
                    float gi = acc[rt][0][r] + xpr[rt][mi][r][0];
                    float gf = acc[rt][1][r] + xpr[rt][mi][r][1];
                    float gg = acc[rt][2][r] + xpr[rt][mi][r][2];
                    float go = acc[rt][3][r] + xpr[rt][mi][r][3];
                    float cn = sigf(gf) * cC[rt][mi][r] + sigf(gi) * tanhf(gg);
                    float hn = sigf(go) * tanhf(cn);
                    cC[rt][mi][r] = cn;
                    h_s[i][(((j >> 2) ^ (i & 7)) << 2) | (j & 3)] = hn;   // swizzled
                }
            }
        }
        __syncthreads();

        // ---- rebuild A-fragments (h_t) from LDS, split bf16 ----
#pragma unroll
        for (int rt = 0; rt < 2; ++rt) {
            int i = rt * 16 + i0;
            int ix7 = i & 7;
#pragma unroll
            for (int kt = 0; kt < 4; ++kt) {
                int b0 = (kt * 8 + q * 2);
                float4 v0 = *(const float4*)&h_s[i][((b0 ^ ix7) << 2)];
                float4 v1 = *(const float4*)&h_s[i][(((b0 + 1) ^ ix7) << 2)];
                float vv[8] = {v0.x, v0.y, v0.z, v0.w, v1.x, v1.y, v1.z, v1.w};
                short8 hi8, lo8;
#pragma unroll
                for (int e = 0; e < 8; ++e) {
                    unsigned short h16 = f2bf(vv[e]);
                    hi8[e] = (short)h16;
                    lo8[e] = (short)f2bf(vv[e] - bf2f(h16));
                }
                Ahi[rt][kt] = hi8;
                Alo[rt][kt] = lo8;
            }
        }

        // ---- pw[n][t][:] = (mask*h_t) @ Wc  (waves 0,1 only) ----
        if (wid < 2) {
            int rt = wid;
            f32x4 p = (f32x4){0.f, 0.f, 0.f, 0.f};
            bool on = (mk[rt] != 0.f);
            short8 zz = (short8)(short)0;
#pragma unroll
            for (int kt = 0; kt < 4; ++kt) {
                short8 ah = on ? Ahi[rt][kt] : zz;
                short8 al = on ? Alo[rt][kt] : zz;
                p = __builtin_amdgcn_mfma_f32_16x16x32_bf16(ah, WcH[kt], p, 0, 0, 0);
                p = __builtin_amdgcn_mfma_f32_16x16x32_bf16(al, WcH[kt], p, 0, 0, 0);
                p = __builtin_amdgcn_mfma_f32_16x16x32_bf16(ah, WcL[kt], p, 0, 0, 0);
            }
#pragma unroll
            for (int r = 0; r < 4; ++r) {
                int n = n0 + rt * 16 + q * 4 + r;
                if (n < Nn) pw[((size_t)n * Tt + t) * NFf + i0] = p[r];
            }
        }
        __syncthreads();   // h_s reads done before next step overwrites
    }
}

// ---------------- aggregate + bias -> out ----------------

__global__ __launch_bounds__(256) void agg_out_k(
    const float* __restrict__ pw, const int* __restrict__ rowptr,
    const int* __restrict__ colsrc, const float* __restrict__ wnorm,
    const float* __restrict__ dinv, const float* __restrict__ bc,
    float* __restrict__ out, int Nn)
{
    int lane = threadIdx.x & 63;
    int n = blockIdx.x * 4 + (threadIdx.x >> 6);
    if (n >= Nn) return;
    float dv = dinv[n];
    float sw = dv * dv;
    const float* pwn = pw + (size_t)n * 192;
    float a0 = pwn[lane] * sw;
    float a1 = pwn[64 + lane] * sw;
    float a2 = pwn[128 + lane] * sw;
    int s0 = rowptr[n], s1 = rowptr[n + 1];
    for (int e = s0; e < s1; ++e) {
        int s = colsrc[e];
        float w = wnorm[e];
        const float* ps = pw + (size_t)s * 192;
        a0 += ps[lane] * w;
        a1 += ps[64 + lane] * w;
        a2 += ps[128 + lane] * w;
    }
    float bcv = bc[lane & 15];
    float* on = out + (size_t)n * 192;
    on[lane]       = a0 + bcv;
    on[64 + lane]  = a1 + bcv;
    on[128 + lane] = a2 + bcv;
}

// ---------------- launcher ----------------

extern "C" void kernel_launch(void* const* d_in, const int* in_sizes, int n_in,
                              void* d_out, int out_size, void* d_ws, size_t ws_size,
                              hipStream_t stream)
{
    const float* z     = (const float*)d_in[0];
    const int*   edge  = (const int*)d_in[1];
    const unsigned char* xmask = (const unsigned char*)d_in[2];
    const float* W_fc2 = (const float*)d_in[3];
    const float* b_fc2 = (const float*)d_in[4];
    const float* W_ih  = (const float*)d_in[5];
    const float* W_hh  = (const float*)d_in[6];
    const float* b_ih  = (const float*)d_in[7];
    const float* b_hh  = (const float*)d_in[8];
    const float* W_gcn = (const float*)d_in[9];
    const float* b_gcn = (const float*)d_in[10];
    const float* W_fc3 = (const float*)d_in[11];
    const float* b_fc3 = (const float*)d_in[12];
    float* out = (float*)d_out;

    const int N = in_sizes[0] / Lz;   // 10000
    const int E = in_sizes[1] / 2;    // 160000
    const int* esrc = edge;
    const int* edst = edge + E;

    char* w = (char*)d_ws;
    auto alloc = [&](size_t bytes) { char* p = w; w += (bytes + 255) & ~(size_t)255; return p; };
    unsigned short* h0hi = (unsigned short*)alloc((size_t)N * Hh * 2);
    unsigned short* h0lo = (unsigned short*)alloc((size_t)N * Hh * 2);
    float* xp2    = (float*)alloc((size_t)N * FH * 4);
    float* pw     = (float*)alloc((size_t)N * Tt * NFf * 4);
    float* mask   = (float*)alloc((size_t)N * 4);
    float* dinv   = (float*)alloc((size_t)N * 4);
    int*   degi   = (int*)alloc((size_t)N * 4);
    int*   rowptr = (int*)alloc((size_t)(N + 1) * 4);
    int*   cursor = (int*)alloc((size_t)N * 4);
    int*   colsrc = (int*)alloc((size_t)E * 4);
    float* wnorm  = (float*)alloc((size_t)E * 4);
    unsigned short* Bhi  = (unsigned short*)alloc((size_t)FH * Hh * 2);
    unsigned short* Wchi = (unsigned short*)alloc(4096 * 2);
    unsigned short* Wclo = (unsigned short*)alloc(4096 * 2);
    float* Wz     = (float*)alloc((size_t)Lz * FH * 4);
    float* bz     = (float*)alloc(FH * 4);
    float* bc     = (float*)alloc(NFf * 4);

    hipMemsetAsync(degi,   0, (size_t)N * 4, stream);
    hipMemsetAsync(cursor, 0, (size_t)N * 4, stream);

    const int b256n = (N + 255) / 256;
    const int b256e = (E + 255) / 256;
    const int nb16  = (N + 15) / 16;
    const int nb32  = (N + 31) / 32;

    node_mask_k<<<b256n, 256, 0, stream>>>(xmask, mask, N);
    deg_count_k<<<b256e, 256, 0, stream>>>(edst, degi, E, N);
    dinv_k<<<b256n, 256, 0, stream>>>(degi, dinv, N);
    scan_k<<<1, 1024, 0, stream>>>(degi, rowptr, N);
    csr_fill_k<<<b256e, 256, 0, stream>>>(esrc, edst, dinv, rowptr, cursor, colsrc, wnorm, E, N);
    pack_whh_k<<<(FH * Hh + 255) / 256, 256, 0, stream>>>(W_hh, Bhi);
    pack_wc_k<<<(4096 + NFf + 255) / 256, 256, 0, stream>>>(W_gcn, W_fc3, b_gcn, b_fc3, Wchi, Wclo, bc);
    fuse_in_k<<<(Lz * FH + FH + 255) / 256, 256, 0, stream>>>(W_fc2, W_ih, b_fc2, b_ih, b_hh, Wz, bz);

    fc2_k<<<nb16, 128, 0, stream>>>(z, W_fc2, b_fc2, h0hi, h0lo, N);
    xproj_k<<<nb16, 128, 0, stream>>>(z, Wz, bz, xp2, N);

    lstm_all_k<<<nb32, 256, 0, stream>>>(xp2, Bhi, Wchi, Wclo, h0hi, h0lo, mask, pw, N);

    agg_out_k<<<(N + 3) / 4, 256, 0, stream>>>(pw, rowptr, colsrc, wnorm, dinv, bc, out, N);
}

// Round 8
// 711.990 us; speedup vs baseline: 1.1483x; 1.1483x over previous
//
#include <hip/hip_runtime.h>
#include <hip/hip_bf16.h>

#define Hh   128
#define FH   512
#define Lz   64
#define Tt   12
#define NFf  16

typedef __attribute__((ext_vector_type(8))) short short8;   // 8 bf16 = 4 VGPRs
typedef __attribute__((ext_vector_type(4))) float f32x4;

__device__ __forceinline__ float sigf(float x) { return 1.0f / (1.0f + __expf(-x)); }
__device__ __forceinline__ unsigned short f2bf(float x) {
    unsigned u = __float_as_uint(x);
    return (unsigned short)((u + 0x7FFF + ((u >> 16) & 1)) >> 16);
}
__device__ __forceinline__ float bf2f(unsigned short s) {
    return __uint_as_float(((unsigned)s) << 16);
}

// ---------------- graph prep ----------------

__global__ void node_mask_k(const unsigned char* __restrict__ xm, float* __restrict__ mask, int Nn)
{
    int n = blockIdx.x * 256 + threadIdx.x;
    if (n >= Nn) return;
    const unsigned int* p = (const unsigned int*)(xm + (size_t)n * 192);
    unsigned int o = 0;
#pragma unroll
    for (int i = 0; i < 48; ++i) o |= p[i];
    mask[n] = o ? 1.0f : 0.0f;
}

__global__ void deg_count_k(const int* __restrict__ dst, int* __restrict__ degi, int E, int Nn)
{
    int e = blockIdx.x * 256 + threadIdx.x;
    if (e >= E) return;
    int d = dst[e]; d = d < 0 ? 0 : (d >= Nn ? Nn - 1 : d);
    atomicAdd(&degi[d], 1);
}

__global__ void dinv_k(const int* __restrict__ degi, float* __restrict__ dinv, int Nn)
{
    int n = blockIdx.x * 256 + threadIdx.x;
    if (n >= Nn) return;
    dinv[n] = rsqrtf((float)(degi[n] + 1)); // +1 self loop
}

__global__ void scan_k(const int* __restrict__ degi, int* __restrict__ rowptr, int Nn)
{
    __shared__ int wsum[16];
    __shared__ int carry;
    int tid = threadIdx.x;           // 1024
    int lane = tid & 63, wid = tid >> 6;
    if (tid == 0) carry = 0;
    __syncthreads();
    for (int base = 0; base < Nn; base += 1024) {
        int i = base + tid;
        int v = (i < Nn) ? degi[i] : 0;
        int x = v;
#pragma unroll
        for (int off = 1; off < 64; off <<= 1) {
            int y = __shfl_up(x, off, 64);
            if (lane >= off) x += y;
        }
        if (lane == 63) wsum[wid] = x;
        __syncthreads();
        if (wid == 0) {
            int s = (lane < 16) ? wsum[lane] : 0;
#pragma unroll
            for (int off = 1; off < 16; off <<= 1) {
                int y = __shfl_up(s, off, 64);
                if (lane >= off) s += y;
            }
            if (lane < 16) wsum[lane] = s;
        }
        __syncthreads();
        int woff = (wid > 0) ? wsum[wid - 1] : 0;
        int inc = carry + woff + x;
        if (i < Nn) rowptr[i + 1] = inc;
        __syncthreads();
        if (tid == 1023) carry = inc;
        __syncthreads();
    }
    if (tid == 0) rowptr[0] = 0;
}

__global__ void csr_fill_k(const int* __restrict__ src, const int* __restrict__ dst,
                           const float* __restrict__ dinv, const int* __restrict__ rowptr,
                           int* __restrict__ cursor, int* __restrict__ colsrc,
                           float* __restrict__ wnorm, int E, int Nn)
{
    int e = blockIdx.x * 256 + threadIdx.x;
    if (e >= E) return;
    int s = src[e]; s = s < 0 ? 0 : (s >= Nn ? Nn - 1 : s);
    int d = dst[e]; d = d < 0 ? 0 : (d >= Nn ? Nn - 1 : d);
    int pos = rowptr[d] + atomicAdd(&cursor[d], 1);
    colsrc[pos] = s;
    wnorm[pos]  = dinv[s] * dinv[d];
}

// ---------------- weight prep ----------------

// Pack W_hh (bf16 hi only) into MFMA B-fragment order.
// frag (ctile c, ktile kt): lane l elem e holds B[kt*32+(l>>4)*8+e][c*16+(l&15)]
// where B[k][j] = W_hh[j][k].  gid = ((c*4+kt)*64+l)*8+e.
__global__ void pack_whh_k(const float* __restrict__ Whh, unsigned short* __restrict__ Bhi)
{
    int gid = blockIdx.x * 256 + threadIdx.x;     // 65536
    if (gid >= FH * Hh) return;
    int e  = gid & 7;
    int l  = (gid >> 3) & 63;
    int kt = (gid >> 9) & 3;
    int c  = gid >> 11;
    int k = kt * 32 + (l >> 4) * 8 + e;
    int j = c * 16 + (l & 15);
    Bhi[gid] = f2bf(Whh[j * Hh + k]);
}

// Wc = W_gcn @ W_fc3 packed into B-frag order (single ctile, 4 kt), split hi/lo.
// Also bc[f] = b_gcn @ W_fc3 + b_fc3.
__global__ void pack_wc_k(const float* __restrict__ Wg, const float* __restrict__ W3,
                          const float* __restrict__ bg, const float* __restrict__ b3,
                          unsigned short* __restrict__ Wchi, unsigned short* __restrict__ Wclo,
                          float* __restrict__ bc)
{
    int gid = blockIdx.x * 256 + threadIdx.x;
    if (gid < 4096) {
        int e = gid & 7, l = (gid >> 3) & 63, kt = gid >> 9;
        int k = kt * 32 + (l >> 4) * 8 + e, f = l & 15;
        const float* a = Wg + k * Hh;
        float s = 0.f;
#pragma unroll 4
        for (int h = 0; h < Hh; ++h) s += a[h] * W3[h * NFf + f];
        unsigned short hi = f2bf(s);
        Wchi[gid] = hi;
        Wclo[gid] = f2bf(s - bf2f(hi));
    } else if (gid < 4096 + NFf) {
        int f = gid - 4096;
        float s = b3[f];
#pragma unroll 4
        for (int h = 0; h < Hh; ++h) s += bg[h] * W3[h * NFf + f];
        bc[f] = s;
    }
}

// Wz[m][j] = sum_k Wf2[m][k]*Wih[j][k] ; bz[j] = sum_k bf2[k]*Wih[j][k] + bih[j] + bhh[j]
__global__ void fuse_in_k(const float* __restrict__ Wf2, const float* __restrict__ Wih,
                          const float* __restrict__ bf2, const float* __restrict__ bih,
                          const float* __restrict__ bhh,
                          float* __restrict__ Wz, float* __restrict__ bz)
{
    int gid = blockIdx.x * 256 + threadIdx.x;
    if (gid < Lz * FH) {
        int m = gid >> 9, j = gid & 511;
        const float* a = Wf2 + m * Hh;
        const float* b = Wih + j * Hh;
        float s = 0.f;
#pragma unroll 4
        for (int k = 0; k < Hh; ++k) s += a[k] * b[k];
        Wz[m * FH + j] = s;
    } else if (gid < Lz * FH + FH) {
        int j = gid - Lz * FH;
        const float* b = Wih + j * Hh;
        float s = bih[j] + bhh[j];
#pragma unroll 4
        for (int k = 0; k < Hh; ++k) s += bf2[k] * b[k];
        bz[j] = s;
    }
}

// ---------------- fc2: h0 = z @ W_fc2 + b (split bf16 out) ----------------

__global__ __launch_bounds__(128) void fc2_k(const float* __restrict__ z, const float* __restrict__ B,
                                             const float* __restrict__ bias,
                                             unsigned short* __restrict__ h0hi,
                                             unsigned short* __restrict__ h0lo, int Nn)
{
    __shared__ float As[16][Lz];
    int n0 = blockIdx.x * 16;
    int tid = threadIdx.x; // 128
    for (int idx = tid; idx < 16 * Lz; idx += 128) {
        int r = idx >> 6, c = idx & 63;
        int n = n0 + r;
        As[r][c] = (n < Nn) ? z[(size_t)n * Lz + c] : 0.f;
    }
    __syncthreads();
    float acc[16];
#pragma unroll
    for (int i = 0; i < 16; ++i) acc[i] = 0.f;
    for (int k = 0; k < Lz; k += 2) {
        float w0 = B[k * Hh + tid];
        float w1 = B[(k + 1) * Hh + tid];
#pragma unroll
        for (int i = 0; i < 16; ++i) {
            float2 a = *(const float2*)&As[i][k];
            acc[i] += a.x * w0 + a.y * w1;
        }
    }
    float bb = bias[tid];
    for (int i = 0; i < 16; ++i) {
        int n = n0 + i;
        if (n < Nn) {
            float v = acc[i] + bb;
            unsigned short hi = f2bf(v);
            size_t off = (size_t)n * Hh + tid;
            h0hi[off] = hi;
            h0lo[off] = f2bf(v - bf2f(hi));
        }
    }
}

// ---------------- xp2 = z @ Wz + bz (biases folded) ----------------

__global__ __launch_bounds__(128) void xproj_k(const float* __restrict__ A, const float* __restrict__ B,
                                               const float* __restrict__ bias, float* __restrict__ C, int Nn)
{
    __shared__ float As[16][Lz];
    int n0 = blockIdx.x * 16;
    int j = threadIdx.x; // 128
    for (int idx = j; idx < 16 * Lz; idx += 128) {
        int r = idx >> 6, c = idx & 63;
        int n = n0 + r;
        As[r][c] = (n < Nn) ? A[(size_t)n * Lz + c] : 0.f;
    }
    __syncthreads();
    float acc[16][4];
#pragma unroll
    for (int r = 0; r < 16; ++r)
#pragma unroll
        for (int q = 0; q < 4; ++q) acc[r][q] = 0.f;
    for (int k0 = 0; k0 < Lz; k0 += 2) {
        float b0[4], b1[4];
#pragma unroll
        for (int q = 0; q < 4; ++q) {
            b0[q] = B[k0 * FH + q * 128 + j];
            b1[q] = B[(k0 + 1) * FH + q * 128 + j];
        }
#pragma unroll
        for (int r = 0; r < 16; ++r) {
            float2 a = *(const float2*)&As[r][k0];
#pragma unroll
            for (int q = 0; q < 4; ++q) acc[r][q] += a.x * b0[q] + a.y * b1[q];
        }
    }
    float bq[4];
#pragma unroll
    for (int q = 0; q < 4; ++q) bq[q] = bias[q * 128 + j];
    for (int r = 0; r < 16; ++r) {
        int n = n0 + r;
        if (n >= Nn) break;
#pragma unroll
        for (int q = 0; q < 4; ++q) C[(size_t)n * FH + q * 128 + j] = acc[r][q] + bq[q];
    }
}

// ---------------- whole-sequence LSTM + pw, one kernel ----------------
// 256 thr / 4 waves, 32 rows/block, all 12 timesteps internal.
// c in registers (matches C/D layout); h via swizzled 16KB LDS transpose;
// xp2 staged ONCE into 64KB LDS gate-interleaved ([row][j*4+g], one b128 read
// per cell) -- keeps persistent VGPR state ~114, no scratch spill (round-7 fix).

__global__ __launch_bounds__(256, 2) void lstm_all_k(
    const float* __restrict__ xp2,
    const unsigned short* __restrict__ Bhi,
    const unsigned short* __restrict__ Wchi, const unsigned short* __restrict__ Wclo,
    const unsigned short* __restrict__ h0hi, const unsigned short* __restrict__ h0lo,
    const float* __restrict__ mask,
    float* __restrict__ pw, int Nn)
{
    __shared__ float h_s[32][128];    // 16KB, 16B-block XOR swizzle on column
    __shared__ float xp_s[32][512];   // 64KB, gate-interleaved [row][jj*4+g]
    int tid = threadIdx.x, l = tid & 63, wid = tid >> 6;
    int n0 = blockIdx.x * 32;
    int i0 = l & 15, q = l >> 4;
    int m0 = wid * 2;

    // stage xp2 -> LDS (coalesced global read, gate-interleaved LDS write)
    for (int idx = tid; idx < 32 * 512; idx += 256) {
        int row = idx >> 9, fc = idx & 511;
        int g = fc >> 7, jj = fc & 127;
        int n = n0 + row;
        xp_s[row][(jj << 2) | g] = (n < Nn) ? xp2[(size_t)n * FH + fc] : 0.f;
    }

    // Wc fragments (held all kernel)
    short8 WcH[4], WcL[4];
#pragma unroll
    for (int kt = 0; kt < 4; ++kt) {
        WcH[kt] = ((const short8*)Wchi)[kt * 64 + l];
        WcL[kt] = ((const short8*)Wclo)[kt * 64 + l];
    }

    // per-rowtile mask (A rows are i0-indexed)
    float mk[2];
#pragma unroll
    for (int rt = 0; rt < 2; ++rt) {
        int n = n0 + rt * 16 + i0;
        mk[rt] = (n < Nn) ? mask[n] : 0.f;
    }

    // initial A-fragments from h0
    short8 Ahi[2][4], Alo[2][4];
#pragma unroll
    for (int rt = 0; rt < 2; ++rt) {
        int row = n0 + rt * 16 + i0; if (row >= Nn) row = Nn - 1;
        const short8* ph = (const short8*)(h0hi + (size_t)row * Hh + q * 8);
        const short8* pl = (const short8*)(h0lo + (size_t)row * Hh + q * 8);
#pragma unroll
        for (int kt = 0; kt < 4; ++kt) { Ahi[rt][kt] = ph[kt * 4]; Alo[rt][kt] = pl[kt * 4]; }
    }

    float cC[2][2][4] = {};   // c state, [rt][mi][r]
    __syncthreads();          // xp_s ready

    for (int t = 0; t < Tt; ++t) {
        // ---- gates GEMM + pointwise, mi-split to bound registers ----
#pragma unroll
        for (int mi = 0; mi < 2; ++mi) {
            f32x4 acc[2][4];
#pragma unroll
            for (int rt = 0; rt < 2; ++rt)
#pragma unroll
                for (int g = 0; g < 4; ++g) acc[rt][g] = (f32x4){0.f, 0.f, 0.f, 0.f};
#pragma unroll
            for (int g = 0; g < 4; ++g) {
                int cidx = g * 8 + m0 + mi;
#pragma unroll
                for (int kt = 0; kt < 4; ++kt) {
                    short8 b = ((const short8*)Bhi)[((cidx << 2) + kt) * 64 + l];
                    acc[0][g] = __builtin_amdgcn_mfma_f32_16x16x32_bf16(Ahi[0][kt], b, acc[0][g], 0, 0, 0);
                    acc[1][g] = __builtin_amdgcn_mfma_f32_16x16x32_bf16(Ahi[1][kt], b, acc[1][g], 0, 0, 0);
                    acc[0][g] = __builtin_amdgcn_mfma_f32_16x16x32_bf16(Alo[0][kt], b, acc[0][g], 0, 0, 0);
                    acc[1][g] = __builtin_amdgcn_mfma_f32_16x16x32_bf16(Alo[1][kt], b, acc[1][g], 0, 0, 0);
                }
            }
            int j = (m0 + mi) * 16 + i0;
#pragma unroll
            for (int rt = 0; rt < 2; ++rt) {
#pragma unroll
                for (int r = 0; r < 4; ++r) {
                    int i = rt * 16 + q * 4 + r;
                    float4 xg = *(const float4*)&xp_s[i][j << 2];   // gates i,f,g,o
                    float gi = acc[rt][0][r] + xg.x;
                    float gf = acc[rt][1][r] + xg.y;
                    float gg = acc[rt][2][r] + xg.z;
                    float go = acc[rt][3][r] + xg.w;
                    float cn = sigf(gf) * cC[rt][mi][r] + sigf(gi) * tanhf(gg);
                    float hn = sigf(go) * tanhf(cn);
                    cC[rt][mi][r] = cn;
                    h_s[i][(((j >> 2) ^ (i & 7)) << 2) | (j & 3)] = hn;   // swizzled
                }
            }
        }
        __syncthreads();

        // ---- rebuild A-fragments (h_t) from LDS, split bf16 ----
#pragma unroll
        for (int rt = 0; rt < 2; ++rt) {
            int i = rt * 16 + i0;
            int ix7 = i & 7;
#pragma unroll
            for (int kt = 0; kt < 4; ++kt) {
                int b0 = (kt * 8 + q * 2);
                float4 v0 = *(const float4*)&h_s[i][((b0 ^ ix7) << 2)];
                float4 v1 = *(const float4*)&h_s[i][(((b0 + 1) ^ ix7) << 2)];
                float vv[8] = {v0.x, v0.y, v0.z, v0.w, v1.x, v1.y, v1.z, v1.w};
                short8 hi8, lo8;
#pragma unroll
                for (int e = 0; e < 8; ++e) {
                    unsigned short h16 = f2bf(vv[e]);
                    hi8[e] = (short)h16;
                    lo8[e] = (short)f2bf(vv[e] - bf2f(h16));
                }
                Ahi[rt][kt] = hi8;
                Alo[rt][kt] = lo8;
            }
        }

        // ---- pw[n][t][:] = (mask*h_t) @ Wc  (waves 0,1 only) ----
        if (wid < 2) {
            int rt = wid;
            f32x4 p = (f32x4){0.f, 0.f, 0.f, 0.f};
            bool on = (mk[rt] != 0.f);
            short8 zz = (short8)(short)0;
#pragma unroll
            for (int kt = 0; kt < 4; ++kt) {
                short8 ah = on ? Ahi[rt][kt] : zz;
                short8 al = on ? Alo[rt][kt] : zz;
                p = __builtin_amdgcn_mfma_f32_16x16x32_bf16(ah, WcH[kt], p, 0, 0, 0);
                p = __builtin_amdgcn_mfma_f32_16x16x32_bf16(al, WcH[kt], p, 0, 0, 0);
                p = __builtin_amdgcn_mfma_f32_16x16x32_bf16(ah, WcL[kt], p, 0, 0, 0);
            }
#pragma unroll
            for (int r = 0; r < 4; ++r) {
                int n = n0 + rt * 16 + q * 4 + r;
                if (n < Nn) pw[((size_t)n * Tt + t) * NFf + i0] = p[r];
            }
        }
        __syncthreads();   // h_s reads done before next step overwrites
    }
}

// ---------------- aggregate + bias -> out ----------------

__global__ __launch_bounds__(256) void agg_out_k(
    const float* __restrict__ pw, const int* __restrict__ rowptr,
    const int* __restrict__ colsrc, const float* __restrict__ wnorm,
    const float* __restrict__ dinv, const float* __restrict__ bc,
    float* __restrict__ out, int Nn)
{
    int lane = threadIdx.x & 63;
    int n = blockIdx.x * 4 + (threadIdx.x >> 6);
    if (n >= Nn) return;
    float dv = dinv[n];
    float sw = dv * dv;
    const float* pwn = pw + (size_t)n * 192;
    float a0 = pwn[lane] * sw;
    float a1 = pwn[64 + lane] * sw;
    float a2 = pwn[128 + lane] * sw;
    int s0 = rowptr[n], s1 = rowptr[n + 1];
    for (int e = s0; e < s1; ++e) {
        int s = colsrc[e];
        float w = wnorm[e];
        const float* ps = pw + (size_t)s * 192;
        a0 += ps[lane] * w;
        a1 += ps[64 + lane] * w;
        a2 += ps[128 + lane] * w;
    }
    float bcv = bc[lane & 15];
    float* on = out + (size_t)n * 192;
    on[lane]       = a0 + bcv;
    on[64 + lane]  = a1 + bcv;
    on[128 + lane] = a2 + bcv;
}

// ---------------- launcher ----------------

extern "C" void kernel_launch(void* const* d_in, const int* in_sizes, int n_in,
                              void* d_out, int out_size, void* d_ws, size_t ws_size,
                              hipStream_t stream)
{
    const float* z     = (const float*)d_in[0];
    const int*   edge  = (const int*)d_in[1];
    const unsigned char* xmask = (const unsigned char*)d_in[2];
    const float* W_fc2 = (const float*)d_in[3];
    const float* b_fc2 = (const float*)d_in[4];
    const float* W_ih  = (const float*)d_in[5];
    const float* W_hh  = (const float*)d_in[6];
    const float* b_ih  = (const float*)d_in[7];
    const float* b_hh  = (const float*)d_in[8];
    const float* W_gcn = (const float*)d_in[9];
    const float* b_gcn = (const float*)d_in[10];
    const float* W_fc3 = (const float*)d_in[11];
    const float* b_fc3 = (const float*)d_in[12];
    float* out = (float*)d_out;

    const int N = in_sizes[0] / Lz;   // 10000
    const int E = in_sizes[1] / 2;    // 160000
    const int* esrc = edge;
    const int* edst = edge + E;

    char* w = (char*)d_ws;
    auto alloc = [&](size_t bytes) { char* p = w; w += (bytes + 255) & ~(size_t)255; return p; };
    unsigned short* h0hi = (unsigned short*)alloc((size_t)N * Hh * 2);
    unsigned short* h0lo = (unsigned short*)alloc((size_t)N * Hh * 2);
    float* xp2    = (float*)alloc((size_t)N * FH * 4);
    float* pw     = (float*)alloc((size_t)N * Tt * NFf * 4);
    float* mask   = (float*)alloc((size_t)N * 4);
    float* dinv   = (float*)alloc((size_t)N * 4);
    int*   degi   = (int*)alloc((size_t)N * 4);
    int*   rowptr = (int*)alloc((size_t)(N + 1) * 4);
    int*   cursor = (int*)alloc((size_t)N * 4);
    int*   colsrc = (int*)alloc((size_t)E * 4);
    float* wnorm  = (float*)alloc((size_t)E * 4);
    unsigned short* Bhi  = (unsigned short*)alloc((size_t)FH * Hh * 2);
    unsigned short* Wchi = (unsigned short*)alloc(4096 * 2);
    unsigned short* Wclo = (unsigned short*)alloc(4096 * 2);
    float* Wz     = (float*)alloc((size_t)Lz * FH * 4);
    float* bz     = (float*)alloc(FH * 4);
    float* bc     = (float*)alloc(NFf * 4);

    hipMemsetAsync(degi,   0, (size_t)N * 4, stream);
    hipMemsetAsync(cursor, 0, (size_t)N * 4, stream);

    const int b256n = (N + 255) / 256;
    const int b256e = (E + 255) / 256;
    const int nb16  = (N + 15) / 16;
    const int nb32  = (N + 31) / 32;

    node_mask_k<<<b256n, 256, 0, stream>>>(xmask, mask, N);
    deg_count_k<<<b256e, 256, 0, stream>>>(edst, degi, E, N);
    dinv_k<<<b256n, 256, 0, stream>>>(degi, dinv, N);
    scan_k<<<1, 1024, 0, stream>>>(degi, rowptr, N);
    csr_fill_k<<<b256e, 256, 0, stream>>>(esrc, edst, dinv, rowptr, cursor, colsrc, wnorm, E, N);
    pack_whh_k<<<(FH * Hh + 255) / 256, 256, 0, stream>>>(W_hh, Bhi);
    pack_wc_k<<<(4096 + NFf + 255) / 256, 256, 0, stream>>>(W_gcn, W_fc3, b_gcn, b_fc3, Wchi, Wclo, bc);
    fuse_in_k<<<(Lz * FH + FH + 255) / 256, 256, 0, stream>>>(W_fc2, W_ih, b_fc2, b_ih, b_hh, Wz, bz);

    fc2_k<<<nb16, 128, 0, stream>>>(z, W_fc2, b_fc2, h0hi, h0lo, N);
    xproj_k<<<nb16, 128, 0, stream>>>(z, Wz, bz, xp2, N);

    lstm_all_k<<<nb32, 256, 0, stream>>>(xp2, Bhi, Wchi, Wclo, h0hi, h0lo, mask, pw, N);

    agg_out_k<<<(N + 3) / 4, 256, 0, stream>>>(pw, rowptr, colsrc, wnorm, dinv, bc, out, N);
}

// Round 9
// 306.237 us; speedup vs baseline: 2.6697x; 2.3250x over previous
//
#include <hip/hip_runtime.h>
#include <hip/hip_bf16.h>

#define Hh   128
#define FH   512
#define Lz   64
#define Tt   12
#define NFf  16

typedef __attribute__((ext_vector_type(8))) short short8;   // 8 bf16 = 4 VGPRs
typedef __attribute__((ext_vector_type(4))) float f32x4;

__device__ __forceinline__ float sigf(float x) { return 1.0f / (1.0f + __expf(-x)); }
__device__ __forceinline__ unsigned short f2bf(float x) {
    unsigned u = __float_as_uint(x);
    return (unsigned short)((u + 0x7FFF + ((u >> 16) & 1)) >> 16);
}
__device__ __forceinline__ float bf2f(unsigned short s) {
    return __uint_as_float(((unsigned)s) << 16);
}

// ---------------- graph prep ----------------

__global__ void node_mask_k(const unsigned char* __restrict__ xm, float* __restrict__ mask, int Nn)
{
    int n = blockIdx.x * 256 + threadIdx.x;
    if (n >= Nn) return;
    const unsigned int* p = (const unsigned int*)(xm + (size_t)n * 192);
    unsigned int o = 0;
#pragma unroll
    for (int i = 0; i < 48; ++i) o |= p[i];
    mask[n] = o ? 1.0f : 0.0f;
}

__global__ void deg_count_k(const int* __restrict__ dst, int* __restrict__ degi, int E, int Nn)
{
    int e = blockIdx.x * 256 + threadIdx.x;
    if (e >= E) return;
    int d = dst[e]; d = d < 0 ? 0 : (d >= Nn ? Nn - 1 : d);
    atomicAdd(&degi[d], 1);
}

__global__ void dinv_k(const int* __restrict__ degi, float* __restrict__ dinv, int Nn)
{
    int n = blockIdx.x * 256 + threadIdx.x;
    if (n >= Nn) return;
    dinv[n] = rsqrtf((float)(degi[n] + 1)); // +1 self loop
}

__global__ void scan_k(const int* __restrict__ degi, int* __restrict__ rowptr, int Nn)
{
    __shared__ int wsum[16];
    __shared__ int carry;
    int tid = threadIdx.x;           // 1024
    int lane = tid & 63, wid = tid >> 6;
    if (tid == 0) carry = 0;
    __syncthreads();
    for (int base = 0; base < Nn; base += 1024) {
        int i = base + tid;
        int v = (i < Nn) ? degi[i] : 0;
        int x = v;
#pragma unroll
        for (int off = 1; off < 64; off <<= 1) {
            int y = __shfl_up(x, off, 64);
            if (lane >= off) x += y;
        }
        if (lane == 63) wsum[wid] = x;
        __syncthreads();
        if (wid == 0) {
            int s = (lane < 16) ? wsum[lane] : 0;
#pragma unroll
            for (int off = 1; off < 16; off <<= 1) {
                int y = __shfl_up(s, off, 64);
                if (lane >= off) s += y;
            }
            if (lane < 16) wsum[lane] = s;
        }
        __syncthreads();
        int woff = (wid > 0) ? wsum[wid - 1] : 0;
        int inc = carry + woff + x;
        if (i < Nn) rowptr[i + 1] = inc;
        __syncthreads();
        if (tid == 1023) carry = inc;
        __syncthreads();
    }
    if (tid == 0) rowptr[0] = 0;
}

__global__ void csr_fill_k(const int* __restrict__ src, const int* __restrict__ dst,
                           const float* __restrict__ dinv, const int* __restrict__ rowptr,
                           int* __restrict__ cursor, int* __restrict__ colsrc,
                           float* __restrict__ wnorm, int E, int Nn)
{
    int e = blockIdx.x * 256 + threadIdx.x;
    if (e >= E) return;
    int s = src[e]; s = s < 0 ? 0 : (s >= Nn ? Nn - 1 : s);
    int d = dst[e]; d = d < 0 ? 0 : (d >= Nn ? Nn - 1 : d);
    int pos = rowptr[d] + atomicAdd(&cursor[d], 1);
    colsrc[pos] = s;
    wnorm[pos]  = dinv[s] * dinv[d];
}

// ---------------- weight prep ----------------

// Pack W_hh (bf16 hi only) into MFMA B-fragment order.
__global__ void pack_whh_k(const float* __restrict__ Whh, unsigned short* __restrict__ Bhi)
{
    int gid = blockIdx.x * 256 + threadIdx.x;     // 65536
    if (gid >= FH * Hh) return;
    int e  = gid & 7;
    int l  = (gid >> 3) & 63;
    int kt = (gid >> 9) & 3;
    int c  = gid >> 11;
    int k = kt * 32 + (l >> 4) * 8 + e;
    int j = c * 16 + (l & 15);
    Bhi[gid] = f2bf(Whh[j * Hh + k]);
}

// Wc = W_gcn @ W_fc3 packed into B-frag order (single ctile, 4 kt), split hi/lo.
__global__ void pack_wc_k(const float* __restrict__ Wg, const float* __restrict__ W3,
                          const float* __restrict__ bg, const float* __restrict__ b3,
                          unsigned short* __restrict__ Wchi, unsigned short* __restrict__ Wclo,
                          float* __restrict__ bc)
{
    int gid = blockIdx.x * 256 + threadIdx.x;
    if (gid < 4096) {
        int e = gid & 7, l = (gid >> 3) & 63, kt = gid >> 9;
        int k = kt * 32 + (l >> 4) * 8 + e, f = l & 15;
        const float* a = Wg + k * Hh;
        float s = 0.f;
#pragma unroll 4
        for (int h = 0; h < Hh; ++h) s += a[h] * W3[h * NFf + f];
        unsigned short hi = f2bf(s);
        Wchi[gid] = hi;
        Wclo[gid] = f2bf(s - bf2f(hi));
    } else if (gid < 4096 + NFf) {
        int f = gid - 4096;
        float s = b3[f];
#pragma unroll 4
        for (int h = 0; h < Hh; ++h) s += bg[h] * W3[h * NFf + f];
        bc[f] = s;
    }
}

// Wz[m][j] = sum_k Wf2[m][k]*Wih[j][k] ; bz[j] = sum_k bf2[k]*Wih[j][k] + bih[j] + bhh[j]
__global__ void fuse_in_k(const float* __restrict__ Wf2, const float* __restrict__ Wih,
                          const float* __restrict__ bf2, const float* __restrict__ bih,
                          const float* __restrict__ bhh,
                          float* __restrict__ Wz, float* __restrict__ bz)
{
    int gid = blockIdx.x * 256 + threadIdx.x;
    if (gid < Lz * FH) {
        int m = gid >> 9, j = gid & 511;
        const float* a = Wf2 + m * Hh;
        const float* b = Wih + j * Hh;
        float s = 0.f;
#pragma unroll 4
        for (int k = 0; k < Hh; ++k) s += a[k] * b[k];
        Wz[m * FH + j] = s;
    } else if (gid < Lz * FH + FH) {
        int j = gid - Lz * FH;
        const float* b = Wih + j * Hh;
        float s = bih[j] + bhh[j];
#pragma unroll 4
        for (int k = 0; k < Hh; ++k) s += bf2[k] * b[k];
        bz[j] = s;
    }
}

// ---------------- fc2: h0 = z @ W_fc2 + b (split bf16 out) ----------------

__global__ __launch_bounds__(128) void fc2_k(const float* __restrict__ z, const float* __restrict__ B,
                                             const float* __restrict__ bias,
                                             unsigned short* __restrict__ h0hi,
                                             unsigned short* __restrict__ h0lo, int Nn)
{
    __shared__ float As[16][Lz];
    int n0 = blockIdx.x * 16;
    int tid = threadIdx.x; // 128
    for (int idx = tid; idx < 16 * Lz; idx += 128) {
        int r = idx >> 6, c = idx & 63;
        int n = n0 + r;
        As[r][c] = (n < Nn) ? z[(size_t)n * Lz + c] : 0.f;
    }
    __syncthreads();
    float acc[16];
#pragma unroll
    for (int i = 0; i < 16; ++i) acc[i] = 0.f;
    for (int k = 0; k < Lz; k += 2) {
        float w0 = B[k * Hh + tid];
        float w1 = B[(k + 1) * Hh + tid];
#pragma unroll
        for (int i = 0; i < 16; ++i) {
            float2 a = *(const float2*)&As[i][k];
            acc[i] += a.x * w0 + a.y * w1;
        }
    }
    float bb = bias[tid];
    for (int i = 0; i < 16; ++i) {
        int n = n0 + i;
        if (n < Nn) {
            float v = acc[i] + bb;
            unsigned short hi = f2bf(v);
            size_t off = (size_t)n * Hh + tid;
            h0hi[off] = hi;
            h0lo[off] = f2bf(v - bf2f(hi));
        }
    }
}

// ---------------- xp2 = z @ Wz + bz (biases folded) ----------------

__global__ __launch_bounds__(128) void xproj_k(const float* __restrict__ A, const float* __restrict__ B,
                                               const float* __restrict__ bias, float* __restrict__ C, int Nn)
{
    __shared__ float As[16][Lz];
    int n0 = blockIdx.x * 16;
    int j = threadIdx.x; // 128
    for (int idx = j; idx < 16 * Lz; idx += 128) {
        int r = idx >> 6, c = idx & 63;
        int n = n0 + r;
        As[r][c] = (n < Nn) ? A[(size_t)n * Lz + c] : 0.f;
    }
    __syncthreads();
    float acc[16][4];
#pragma unroll
    for (int r = 0; r < 16; ++r)
#pragma unroll
        for (int q = 0; q < 4; ++q) acc[r][q] = 0.f;
    for (int k0 = 0; k0 < Lz; k0 += 2) {
        float b0[4], b1[4];
#pragma unroll
        for (int q = 0; q < 4; ++q) {
            b0[q] = B[k0 * FH + q * 128 + j];
            b1[q] = B[(k0 + 1) * FH + q * 128 + j];
        }
#pragma unroll
        for (int r = 0; r < 16; ++r) {
            float2 a = *(const float2*)&As[r][k0];
#pragma unroll
            for (int q = 0; q < 4; ++q) acc[r][q] += a.x * b0[q] + a.y * b1[q];
        }
    }
    float bq[4];
#pragma unroll
    for (int q = 0; q < 4; ++q) bq[q] = bias[q * 128 + j];
    for (int r = 0; r < 16; ++r) {
        int n = n0 + r;
        if (n >= Nn) break;
#pragma unroll
        for (int q = 0; q < 4; ++q) C[(size_t)n * FH + q * 128 + j] = acc[r][q] + bq[q];
    }
}

// ---------------- whole-sequence LSTM + pw, one kernel ----------------
// 256 thr / 4 waves, 32 rows/block, all 12 timesteps internal.
// ALL register arrays are compile-time indexed (rule #20): the pw step is
// duplicated per-wave with literal rt indices -- no scratch demotion.

__global__ __launch_bounds__(256, 2) void lstm_all_k(
    const float* __restrict__ xp2,
    const unsigned short* __restrict__ Bhi,
    const unsigned short* __restrict__ Wchi, const unsigned short* __restrict__ Wclo,
    const unsigned short* __restrict__ h0hi, const unsigned short* __restrict__ h0lo,
    const float* __restrict__ mask,
    float* __restrict__ pw, int Nn)
{
    __shared__ float h_s[32][128];    // 16KB, 16B-block XOR swizzle on column
    __shared__ float xp_s[32][512];   // 64KB, gate-interleaved [row][jj*4+g]
    int tid = threadIdx.x, l = tid & 63, wid = tid >> 6;
    int n0 = blockIdx.x * 32;
    int i0 = l & 15, q = l >> 4;
    int m0 = wid * 2;

    // stage xp2 -> LDS (coalesced global read, gate-interleaved LDS write)
    for (int idx = tid; idx < 32 * 512; idx += 256) {
        int row = idx >> 9, fc = idx & 511;
        int g = fc >> 7, jj = fc & 127;
        int n = n0 + row;
        xp_s[row][(jj << 2) | g] = (n < Nn) ? xp2[(size_t)n * FH + fc] : 0.f;
    }

    // Wc fragments (held all kernel)
    short8 WcH[4], WcL[4];
#pragma unroll
    for (int kt = 0; kt < 4; ++kt) {
        WcH[kt] = ((const short8*)Wchi)[kt * 64 + l];
        WcL[kt] = ((const short8*)Wclo)[kt * 64 + l];
    }

    // per-rowtile mask (scalars, not an array -> no runtime indexing)
    float mk0, mk1;
    { int n = n0 + i0;      mk0 = (n < Nn) ? mask[n] : 0.f; }
    { int n = n0 + 16 + i0; mk1 = (n < Nn) ? mask[n] : 0.f; }

    // initial A-fragments from h0
    short8 Ahi[2][4], Alo[2][4];
#pragma unroll
    for (int rt = 0; rt < 2; ++rt) {
        int row = n0 + rt * 16 + i0; if (row >= Nn) row = Nn - 1;
        const short8* ph = (const short8*)(h0hi + (size_t)row * Hh + q * 8);
        const short8* pl = (const short8*)(h0lo + (size_t)row * Hh + q * 8);
#pragma unroll
        for (int kt = 0; kt < 4; ++kt) { Ahi[rt][kt] = ph[kt * 4]; Alo[rt][kt] = pl[kt * 4]; }
    }

    float cC[2][2][4] = {};   // c state, [rt][mi][r]
    __syncthreads();          // xp_s ready

    for (int t = 0; t < Tt; ++t) {
        // ---- gates GEMM + pointwise, mi-split to bound registers ----
#pragma unroll
        for (int mi = 0; mi < 2; ++mi) {
            f32x4 acc[2][4];
#pragma unroll
            for (int rt = 0; rt < 2; ++rt)
#pragma unroll
                for (int g = 0; g < 4; ++g) acc[rt][g] = (f32x4){0.f, 0.f, 0.f, 0.f};
#pragma unroll
            for (int g = 0; g < 4; ++g) {
                int cidx = g * 8 + m0 + mi;
#pragma unroll
                for (int kt = 0; kt < 4; ++kt) {
                    short8 b = ((const short8*)Bhi)[((cidx << 2) + kt) * 64 + l];
                    acc[0][g] = __builtin_amdgcn_mfma_f32_16x16x32_bf16(Ahi[0][kt], b, acc[0][g], 0, 0, 0);
                    acc[1][g] = __builtin_amdgcn_mfma_f32_16x16x32_bf16(Ahi[1][kt], b, acc[1][g], 0, 0, 0);
                    acc[0][g] = __builtin_amdgcn_mfma_f32_16x16x32_bf16(Alo[0][kt], b, acc[0][g], 0, 0, 0);
                    acc[1][g] = __builtin_amdgcn_mfma_f32_16x16x32_bf16(Alo[1][kt], b, acc[1][g], 0, 0, 0);
                }
            }
            int j = (m0 + mi) * 16 + i0;
#pragma unroll
            for (int rt = 0; rt < 2; ++rt) {
#pragma unroll
                for (int r = 0; r < 4; ++r) {
                    int i = rt * 16 + q * 4 + r;
                    float4 xg = *(const float4*)&xp_s[i][j << 2];   // gates i,f,g,o
                    float gi = acc[rt][0][r] + xg.x;
                    float gf = acc[rt][1][r] + xg.y;
                    float gg = acc[rt][2][r] + xg.z;
                    float go = acc[rt][3][r] + xg.w;
                    float cn = sigf(gf) * cC[rt][mi][r] + sigf(gi) * tanhf(gg);
                    float hn = sigf(go) * tanhf(cn);
                    cC[rt][mi][r] = cn;
                    h_s[i][(((j >> 2) ^ (i & 7)) << 2) | (j & 3)] = hn;   // swizzled
                }
            }
        }
        __syncthreads();

        // ---- rebuild A-fragments (h_t) from LDS, split bf16 ----
#pragma unroll
        for (int rt = 0; rt < 2; ++rt) {
            int i = rt * 16 + i0;
            int ix7 = i & 7;
#pragma unroll
            for (int kt = 0; kt < 4; ++kt) {
                int b0 = (kt * 8 + q * 2);
                float4 v0 = *(const float4*)&h_s[i][((b0 ^ ix7) << 2)];
                float4 v1 = *(const float4*)&h_s[i][(((b0 + 1) ^ ix7) << 2)];
                float vv[8] = {v0.x, v0.y, v0.z, v0.w, v1.x, v1.y, v1.z, v1.w};
                short8 hi8, lo8;
#pragma unroll
                for (int e = 0; e < 8; ++e) {
                    unsigned short h16 = f2bf(vv[e]);
                    hi8[e] = (short)h16;
                    lo8[e] = (short)f2bf(vv[e] - bf2f(h16));
                }
                Ahi[rt][kt] = hi8;
                Alo[rt][kt] = lo8;
            }
        }

        // ---- pw[n][t][:] = (mask*h_t) @ Wc ----
        // Compile-time rt per wave (rule #20: no runtime indexing of reg arrays).
#define PW_STEP(RT, MK)                                                              \
        {                                                                            \
            f32x4 p = (f32x4){0.f, 0.f, 0.f, 0.f};                                   \
            bool on = ((MK) != 0.f);                                                 \
            short8 zz = (short8)(short)0;                                            \
            _Pragma("unroll")                                                        \
            for (int kt = 0; kt < 4; ++kt) {                                         \
                short8 ah = on ? Ahi[RT][kt] : zz;                                   \
                short8 al = on ? Alo[RT][kt] : zz;                                   \
                p = __builtin_amdgcn_mfma_f32_16x16x32_bf16(ah, WcH[kt], p, 0, 0, 0);\
                p = __builtin_amdgcn_mfma_f32_16x16x32_bf16(al, WcH[kt], p, 0, 0, 0);\
                p = __builtin_amdgcn_mfma_f32_16x16x32_bf16(ah, WcL[kt], p, 0, 0, 0);\
            }                                                                        \
            _Pragma("unroll")                                                        \
            for (int r = 0; r < 4; ++r) {                                            \
                int n = n0 + (RT) * 16 + q * 4 + r;                                  \
                if (n < Nn) pw[((size_t)n * Tt + t) * NFf + i0] = p[r];              \
            }                                                                        \
        }
        if (wid == 0)      PW_STEP(0, mk0)
        else if (wid == 1) PW_STEP(1, mk1)
#undef PW_STEP
        __syncthreads();   // h_s reads done before next step overwrites
    }
}

// ---------------- aggregate + bias -> out ----------------

__global__ __launch_bounds__(256) void agg_out_k(
    const float* __restrict__ pw, const int* __restrict__ rowptr,
    const int* __restrict__ colsrc, const float* __restrict__ wnorm,
    const float* __restrict__ dinv, const float* __restrict__ bc,
    float* __restrict__ out, int Nn)
{
    int lane = threadIdx.x & 63;
    int n = blockIdx.x * 4 + (threadIdx.x >> 6);
    if (n >= Nn) return;
    float dv = dinv[n];
    float sw = dv * dv;
    const float* pwn = pw + (size_t)n * 192;
    float a0 = pwn[lane] * sw;
    float a1 = pwn[64 + lane] * sw;
    float a2 = pwn[128 + lane] * sw;
    int s0 = rowptr[n], s1 = rowptr[n + 1];
    for (int e = s0; e < s1; ++e) {
        int s = colsrc[e];
        float w = wnorm[e];
        const float* ps = pw + (size_t)s * 192;
        a0 += ps[lane] * w;
        a1 += ps[64 + lane] * w;
        a2 += ps[128 + lane] * w;
    }
    float bcv = bc[lane & 15];
    float* on = out + (size_t)n * 192;
    on[lane]       = a0 + bcv;
    on[64 + lane]  = a1 + bcv;
    on[128 + lane] = a2 + bcv;
}

// ---------------- launcher ----------------

extern "C" void kernel_launch(void* const* d_in, const int* in_sizes, int n_in,
                              void* d_out, int out_size, void* d_ws, size_t ws_size,
                              hipStream_t stream)
{
    const float* z     = (const float*)d_in[0];
    const int*   edge  = (const int*)d_in[1];
    const unsigned char* xmask = (const unsigned char*)d_in[2];
    const float* W_fc2 = (const float*)d_in[3];
    const float* b_fc2 = (const float*)d_in[4];
    const float* W_ih  = (const float*)d_in[5];
    const float* W_hh  = (const float*)d_in[6];
    const float* b_ih  = (const float*)d_in[7];
    const float* b_hh  = (const float*)d_in[8];
    const float* W_gcn = (const float*)d_in[9];
    const float* b_gcn = (const float*)d_in[10];
    const float* W_fc3 = (const float*)d_in[11];
    const float* b_fc3 = (const float*)d_in[12];
    float* out = (float*)d_out;

    const int N = in_sizes[0] / Lz;   // 10000
    const int E = in_sizes[1] / 2;    // 160000
    const int* esrc = edge;
    const int* edst = edge + E;

    char* w = (char*)d_ws;
    auto alloc = [&](size_t bytes) { char* p = w; w += (bytes + 255) & ~(size_t)255; return p; };
    unsigned short* h0hi = (unsigned short*)alloc((size_t)N * Hh * 2);
    unsigned short* h0lo = (unsigned short*)alloc((size_t)N * Hh * 2);
    float* xp2    = (float*)alloc((size_t)N * FH * 4);
    float* pw     = (float*)alloc((size_t)N * Tt * NFf * 4);
    float* mask   = (float*)alloc((size_t)N * 4);
    float* dinv   = (float*)alloc((size_t)N * 4);
    int*   degi   = (int*)alloc((size_t)N * 4);
    int*   rowptr = (int*)alloc((size_t)(N + 1) * 4);
    int*   cursor = (int*)alloc((size_t)N * 4);
    int*   colsrc = (int*)alloc((size_t)E * 4);
    float* wnorm  = (float*)alloc((size_t)E * 4);
    unsigned short* Bhi  = (unsigned short*)alloc((size_t)FH * Hh * 2);
    unsigned short* Wchi = (unsigned short*)alloc(4096 * 2);
    unsigned short* Wclo = (unsigned short*)alloc(4096 * 2);
    float* Wz     = (float*)alloc((size_t)Lz * FH * 4);
    float* bz     = (float*)alloc(FH * 4);
    float* bc     = (float*)alloc(NFf * 4);

    hipMemsetAsync(degi,   0, (size_t)N * 4, stream);
    hipMemsetAsync(cursor, 0, (size_t)N * 4, stream);

    const int b256n = (N + 255) / 256;
    const int b256e = (E + 255) / 256;
    const int nb16  = (N + 15) / 16;
    const int nb32  = (N + 31) / 32;

    node_mask_k<<<b256n, 256, 0, stream>>>(xmask, mask, N);
    deg_count_k<<<b256e, 256, 0, stream>>>(edst, degi, E, N);
    dinv_k<<<b256n, 256, 0, stream>>>(degi, dinv, N);
    scan_k<<<1, 1024, 0, stream>>>(degi, rowptr, N);
    csr_fill_k<<<b256e, 256, 0, stream>>>(esrc, edst, dinv, rowptr, cursor, colsrc, wnorm, E, N);
    pack_whh_k<<<(FH * Hh + 255) / 256, 256, 0, stream>>>(W_hh, Bhi);
    pack_wc_k<<<(4096 + NFf + 255) / 256, 256, 0, stream>>>(W_gcn, W_fc3, b_gcn, b_fc3, Wchi, Wclo, bc);
    fuse_in_k<<<(Lz * FH + FH + 255) / 256, 256, 0, stream>>>(W_fc2, W_ih, b_fc2, b_ih, b_hh, Wz, bz);

    fc2_k<<<nb16, 128, 0, stream>>>(z, W_fc2, b_fc2, h0hi, h0lo, N);
    xproj_k<<<nb16, 128, 0, stream>>>(z, Wz, bz, xp2, N);

    lstm_all_k<<<nb32, 256, 0, stream>>>(xp2, Bhi, Wchi, Wclo, h0hi, h0lo, mask, pw, N);

    agg_out_k<<<(N + 3) / 4, 256, 0, stream>>>(pw, rowptr, colsrc, wnorm, dinv, bc, out, N);
}